// Round 1
// baseline (653.306 us; speedup 1.0000x reference)
//
#include <hip/hip_runtime.h>
#include <hip/hip_bf16.h>

#define FFT_N     4096
#define FFT_LOG2N 12
#define THREADS   256

__global__ __launch_bounds__(THREADS) void afdf_fft_kernel(
    const float* __restrict__ x,   // (B, C, 2)
    const float* __restrict__ A,   // (1, C, 2)
    const float* __restrict__ D,   // (1, C, 2)
    float* __restrict__ out)       // (B, C, 2)
{
    __shared__ float2 data[FFT_N];        // 32 KB
    __shared__ float2 tw[FFT_N / 2];      // 16 KB: tw[k] = exp(-2*pi*i*k/N)

    const int row = blockIdx.x;
    const int tid = threadIdx.x;

    const float2* __restrict__ xr = (const float2*)x + (size_t)row * FFT_N;
    const float2* __restrict__ Ac = (const float2*)A;
    const float2* __restrict__ Dc = (const float2*)D;
    float2* __restrict__ o        = (float2*)out + (size_t)row * FFT_N;

    // --- twiddle table (once per block; 8 sincos per thread) ---
    const float w0 = -6.283185307179586f / (float)FFT_N;
    for (int k = tid; k < FFT_N / 2; k += THREADS) {
        float ang = w0 * (float)k;
        tw[k] = make_float2(cosf(ang), sinf(ang));
    }

    // --- load row, scale by A elementwise (re,im independently) ---
    for (int c = tid; c < FFT_N; c += THREADS) {
        float2 v = xr[c];
        float2 a = Ac[c];
        data[c] = make_float2(a.x * v.x, a.y * v.y);
    }
    __syncthreads();

    // --- forward FFT: radix-2 DIF (natural in -> bit-reversed out) ---
    for (int s = FFT_LOG2N; s >= 1; --s) {
        const int half = 1 << (s - 1);
        const int m    = half << 1;
        for (int k = tid; k < FFT_N / 2; k += THREADS) {
            const int j   = k >> (s - 1);
            const int pos = k & (half - 1);
            const int i0  = j * m + pos;
            const int i1  = i0 + half;
            float2 u = data[i0];
            float2 v = data[i1];
            float2 sum = make_float2(u.x + v.x, u.y + v.y);
            float2 dif = make_float2(u.x - v.x, u.y - v.y);
            float2 w   = tw[pos << (FFT_LOG2N - s)];  // exp(-2*pi*i*pos/m)
            data[i0] = sum;
            data[i1] = make_float2(w.x * dif.x - w.y * dif.y,
                                   w.x * dif.y + w.y * dif.x);
        }
        __syncthreads();
    }

    // --- scale by D (re,im independently); slot p holds freq bitrev(p) ---
    for (int p = tid; p < FFT_N; p += THREADS) {
        const int c = (int)(__brev((unsigned)p) >> (32 - FFT_LOG2N));
        float2 d = Dc[c];
        float2 v = data[p];
        data[p] = make_float2(d.x * v.x, d.y * v.y);
    }
    __syncthreads();

    // --- inverse FFT: radix-2 DIT, conj twiddles (bit-rev in -> natural out) ---
    for (int s = 1; s <= FFT_LOG2N; ++s) {
        const int half = 1 << (s - 1);
        const int m    = half << 1;
        for (int k = tid; k < FFT_N / 2; k += THREADS) {
            const int j   = k >> (s - 1);
            const int pos = k & (half - 1);
            const int i0  = j * m + pos;
            const int i1  = i0 + half;
            float2 u = data[i0];
            float2 v = data[i1];
            float2 w = tw[pos << (FFT_LOG2N - s)];    // conj applied below
            float2 t = make_float2(w.x * v.x + w.y * v.y,    // (w.x,-w.y)*(v.x,v.y)
                                   w.x * v.y - w.y * v.x);
            data[i0] = make_float2(u.x + t.x, u.y + t.y);
            data[i1] = make_float2(u.x - t.x, u.y - t.y);
        }
        __syncthreads();
    }

    // --- store with 1/N normalization ---
    const float inv = 1.0f / (float)FFT_N;
    for (int c = tid; c < FFT_N; c += THREADS) {
        float2 v = data[c];
        o[c] = make_float2(v.x * inv, v.y * inv);
    }
}

extern "C" void kernel_launch(void* const* d_in, const int* in_sizes, int n_in,
                              void* d_out, int out_size, void* d_ws, size_t ws_size,
                              hipStream_t stream) {
    (void)in_sizes; (void)n_in; (void)out_size; (void)d_ws; (void)ws_size;
    const float* x = (const float*)d_in[0];
    const float* A = (const float*)d_in[1];
    const float* D = (const float*)d_in[2];
    float* out = (float*)d_out;

    const int B = 8192;
    afdf_fft_kernel<<<dim3(B), dim3(THREADS), 0, stream>>>(x, A, D, out);
}

// Round 2
// 496.763 us; speedup vs baseline: 1.3151x; 1.3151x over previous
//
#include <hip/hip_runtime.h>
#include <hip/hip_bf16.h>

#define FFT_N   4096
#define THREADS 256

__device__ __forceinline__ float2 cmul(float2 a, float2 b) {
    return make_float2(a.x*b.x - a.y*b.y, a.x*b.y + a.y*b.x);
}
__device__ __forceinline__ float2 cadd(float2 a, float2 b){ return make_float2(a.x+b.x, a.y+b.y); }
__device__ __forceinline__ float2 csub(float2 a, float2 b){ return make_float2(a.x-b.x, a.y-b.y); }

// multiply by S*i  (S=-1: forward, S=+1: inverse)
template<int S>
__device__ __forceinline__ float2 muli(float2 z) {
    return (S < 0) ? make_float2(z.y, -z.x) : make_float2(-z.y, z.x);
}

// 4-point DFT: y[k] = sum_n a_n exp(S*2pi*i*n*k/4)
template<int S>
__device__ __forceinline__ void dft4(float2 a0, float2 a1, float2 a2, float2 a3,
                                     float2& y0, float2& y1, float2& y2, float2& y3) {
    float2 e0 = cadd(a0, a2), e1 = cadd(a1, a3);
    float2 o0 = csub(a0, a2), o1 = muli<S>(csub(a1, a3));
    y0 = cadd(e0, e1); y2 = csub(e0, e1);
    y1 = cadd(o0, o1); y3 = csub(o0, o1);
}

// 16-point DFT in registers: a[k] <- sum_n a[n] exp(S*2pi*i*n*k/16)
template<int S>
__device__ __forceinline__ void dft16(float2* a) {
    const float C1 = 0.92387953251128674f;   // cos(pi/8)
    const float S1 = 0.38268343236508978f;   // sin(pi/8)
    const float R2 = 0.70710678118654752f;
    const float sg = (S < 0) ? -1.0f : 1.0f;
    const float2 w1 = make_float2( C1,  sg*S1);
    const float2 w2 = make_float2( R2,  sg*R2);
    const float2 w3 = make_float2( S1,  sg*C1);
    const float2 w6 = make_float2(-R2,  sg*R2);
    const float2 w9 = make_float2(-C1, -sg*S1);
    float2 t[16];
    // inner DFT4 over n1 of a[4*n1 + n2] -> t[n2*4 + k1]
    dft4<S>(a[0], a[4], a[8],  a[12], t[0],  t[1],  t[2],  t[3]);
    dft4<S>(a[1], a[5], a[9],  a[13], t[4],  t[5],  t[6],  t[7]);
    dft4<S>(a[2], a[6], a[10], a[14], t[8],  t[9],  t[10], t[11]);
    dft4<S>(a[3], a[7], a[11], a[15], t[12], t[13], t[14], t[15]);
    // twiddle: t[n2*4+k1] *= W16^{S*n2*k1}
    t[5]  = cmul(t[5],  w1);  t[6]  = cmul(t[6],  w2);  t[7]  = cmul(t[7],  w3);
    t[9]  = cmul(t[9],  w2);  t[10] = muli<S>(t[10]);   t[11] = cmul(t[11], w6);
    t[13] = cmul(t[13], w3);  t[14] = cmul(t[14], w6);  t[15] = cmul(t[15], w9);
    // outer DFT4 over n2 per k1 -> a[4*k2 + k1]
    dft4<S>(t[0], t[4], t[8],  t[12], a[0], a[4], a[8],  a[12]);
    dft4<S>(t[1], t[5], t[9],  t[13], a[1], a[5], a[9],  a[13]);
    dft4<S>(t[2], t[6], t[10], t[14], a[2], a[6], a[10], a[14]);
    dft4<S>(t[3], t[7], t[11], t[15], a[3], a[7], a[11], a[15]);
}

// R[k] *= exp(S*2pi*i*p*k/M), k=1..15, via one sincos + recurrence
template<int S>
__device__ __forceinline__ void twiddle_apply(float2* R, int p, float invM) {
    float ang = ((S < 0) ? -6.283185307179586f : 6.283185307179586f) * (float)p * invM;
    float s, c;
    __sincosf(ang, &s, &c);
    float2 w1 = make_float2(c, s);
    float2 w = w1;
    R[1] = cmul(R[1], w);
    #pragma unroll
    for (int k = 2; k < 16; ++k) { w = cmul(w, w1); R[k] = cmul(R[k], w); }
}

// padded LDS index: +1 float2 per 16 to break stride-16/256 bank patterns
__device__ __forceinline__ int pidx(int i) { return i + (i >> 4); }

__global__ __launch_bounds__(THREADS, 4) void afdf_fft_kernel(
    const float* __restrict__ x,   // (B, 4096, 2)
    const float* __restrict__ A,   // (1, 4096, 2)
    const float* __restrict__ D,   // (1, 4096, 2)
    float* __restrict__ out)       // (B, 4096, 2)
{
    __shared__ float2 sh[4352];    // 4096 + 256 pad = 34816 B

    const int t = threadIdx.x;
    const size_t rb = (size_t)blockIdx.x * FFT_N;
    const float2* __restrict__ xr = (const float2*)x + rb;
    const float2* __restrict__ Ac = (const float2*)A;
    const float2* __restrict__ Dc = (const float2*)D;
    float2* __restrict__ o        = (float2*)out + rb;

    float2 r[16];

    // ---- Phase A: global load + A-scale + S1 (16-pt DFT over stride-256) ----
    {
        const int p = t;
        #pragma unroll
        for (int n1 = 0; n1 < 16; ++n1) {
            float2 v = xr[p + 256*n1];
            float2 a = Ac[p + 256*n1];
            r[n1] = make_float2(a.x*v.x, a.y*v.y);
        }
        dft16<-1>(r);
        twiddle_apply<-1>(r, p, 1.0f/4096.0f);          // W4096^{p*k}
        #pragma unroll
        for (int k = 0; k < 16; ++k) sh[pidx(p + 256*k)] = r[k];
    }
    __syncthreads();

    // ---- Phase B: S2 (within 256-blocks, stride 16) ----
    {
        const int b = t >> 4, p2 = t & 15, base = b*256;
        #pragma unroll
        for (int n1 = 0; n1 < 16; ++n1) r[n1] = sh[pidx(base + p2 + 16*n1)];
        dft16<-1>(r);
        twiddle_apply<-1>(r, p2, 1.0f/256.0f);          // W256^{p2*k}
        #pragma unroll
        for (int k = 0; k < 16; ++k) sh[pidx(base + p2 + 16*k)] = r[k];
    }
    __syncthreads();

    // ---- Phase C: S3 + D-scale + S3^-1, all in registers ----
    {
        const int base = 16*t;
        #pragma unroll
        for (int n = 0; n < 16; ++n) r[n] = sh[pidx(base + n)];
        dft16<-1>(r);
        // slot k3 holds frequency q = 256*k3 + 16*k2 + k1
        const int k1 = t >> 4, k2 = t & 15;
        #pragma unroll
        for (int k3 = 0; k3 < 16; ++k3) {
            float2 d = Dc[256*k3 + 16*k2 + k1];
            r[k3] = make_float2(d.x*r[k3].x, d.y*r[k3].y);
        }
        dft16<+1>(r);
        #pragma unroll
        for (int n = 0; n < 16; ++n) sh[pidx(base + n)] = r[n];
    }
    __syncthreads();

    // ---- Phase D: S2^-1 (un-twiddle, conj DFT, stride 16) ----
    {
        const int b = t >> 4, p2 = t & 15, base = b*256;
        #pragma unroll
        for (int k = 0; k < 16; ++k) r[k] = sh[pidx(base + p2 + 16*k)];
        twiddle_apply<+1>(r, p2, 1.0f/256.0f);
        dft16<+1>(r);
        #pragma unroll
        for (int n1 = 0; n1 < 16; ++n1) sh[pidx(base + p2 + 16*n1)] = r[n1];
    }
    __syncthreads();

    // ---- Phase E: S1^-1 + 1/N + store ----
    {
        const int p = t;
        #pragma unroll
        for (int k = 0; k < 16; ++k) r[k] = sh[pidx(p + 256*k)];
        twiddle_apply<+1>(r, p, 1.0f/4096.0f);
        dft16<+1>(r);
        const float inv = 1.0f / 4096.0f;
        #pragma unroll
        for (int n1 = 0; n1 < 16; ++n1)
            o[p + 256*n1] = make_float2(r[n1].x*inv, r[n1].y*inv);
    }
}

extern "C" void kernel_launch(void* const* d_in, const int* in_sizes, int n_in,
                              void* d_out, int out_size, void* d_ws, size_t ws_size,
                              hipStream_t stream) {
    (void)in_sizes; (void)n_in; (void)out_size; (void)d_ws; (void)ws_size;
    const float* x = (const float*)d_in[0];
    const float* A = (const float*)d_in[1];
    const float* D = (const float*)d_in[2];
    float* out = (float*)d_out;

    afdf_fft_kernel<<<dim3(8192), dim3(THREADS), 0, stream>>>(x, A, D, out);
}